// Round 17
// baseline (109.534 us; speedup 1.0000x reference)
//
#include <hip/hip_runtime.h>

#define BB 4
#define CC 17
#define NN 4096
#define KN 7
#define NPTS (BB*NN)             // 16384
#define PAIRS (NPTS*KN)          // 114688
#define TT (CC*CC)               // 289
#define FINF 3.4e38f
#define RPB 64                   // rows per knn block (4 waves x 16 rows)
#define SL 8                     // candidate slices per batch
#define CSW 512                  // candidates per slice
#define NGRP 8                   // groups of 4 tiles (32 tiles)
#define SCAP 24                  // per-(row,slice) survivor cap (global)
#define TSL (SL*SCAP)            // 192 survivor slots per row
#define TDW 160                  // bf16 T row: 320 elems = 160 dwords
#define KNNBLKS ((NPTS/RPB)*SL)  // 2048
#define TBLKS ((NPTS*TDW)/256)   // 10240

typedef float f32x4 __attribute__((ext_vector_type(4)));
typedef short short8 __attribute__((ext_vector_type(8)));

__device__ __forceinline__ unsigned int rne_bf16(float x) {
    unsigned int u = __float_as_uint(x);
    return (u + 0x7FFFu + ((u >> 16) & 1u)) >> 16;
}

__device__ __forceinline__ bool lexless(float ad, int ai, float bd, int bi) {
    return (ad < bd) || (ad == bd && ai < bi);
}

// ---- Stage 1: logits -> xs fp32[.][24] (slot20=sq), xbA[.][32], xbB[.][24];
//      zero gcnt + zbuf ------------------------------------------------------
__global__ __launch_bounds__(256) void prep_kernel(const float* __restrict__ logits,
                                                   float* __restrict__ xs,
                                                   unsigned short* __restrict__ xbA,
                                                   unsigned short* __restrict__ xbB,
                                                   unsigned int* __restrict__ zbuf,
                                                   int* __restrict__ gcnt) {
    if (blockIdx.x == 0) {
        for (int e = threadIdx.x; e < 768; e += 256) zbuf[e] = 0u;
    }
    int i = blockIdx.x * 256 + threadIdx.x;
    if (i >= NPTS) return;
#pragma unroll
    for (int q = 0; q < SL; ++q) gcnt[i * SL + q] = 0;

    int b = i >> 12;
    int n = i & (NN - 1);
    const float* base = logits + (size_t)b * CC * NN + n;
    float v[24];
    float s = 0.f;
#pragma unroll
    for (int c = 0; c < CC; ++c) { v[c] = base[(size_t)c * NN]; s = fmaf(v[c], v[c], s); }
#pragma unroll
    for (int c = CC; c < 24; ++c) v[c] = 0.f;
    v[20] = s;                                   // sq folded into xs slot 20
    float4* dst = (float4*)(xs + (size_t)i * 24);
#pragma unroll
    for (int q = 0; q < 6; ++q)
        dst[q] = make_float4(v[4*q], v[4*q+1], v[4*q+2], v[4*q+3]);

    unsigned int w[12];
#pragma unroll
    for (int t = 0; t < 8; ++t)
        w[t] = rne_bf16(v[2*t]) | (rne_bf16(v[2*t+1]) << 16);
#pragma unroll
    for (int t = 9; t < 12; ++t) w[t] = 0u;
    // A view (64 B rows): slot16 = v16, slot17 = 1.0, rest zero
    w[8] = rne_bf16(v[16]) | (0x3F80u << 16);
    uint4* da = (uint4*)(xbA + (size_t)i * 32);
    da[0] = make_uint4(w[0], w[1], w[2], w[3]);
    da[1] = make_uint4(w[4], w[5], w[6], w[7]);
    da[2] = make_uint4(w[8], w[9], w[10], w[11]);
    da[3] = make_uint4(0u, 0u, 0u, 0u);
    // B view (48 B rows): slot17 = -sq/2 => acc = dot - sq_c/2
    w[8] = rne_bf16(v[16]) | (rne_bf16(-0.5f * s) << 16);
    uint4* db = (uint4*)(xbB + (size_t)i * 24);
    db[0] = make_uint4(w[0], w[1], w[2], w[3]);
    db[1] = make_uint4(w[4], w[5], w[6], w[7]);
    db[2] = make_uint4(w[8], w[9], w[10], w[11]);
}

// branchless sorted-desc top-4 insert; packed floats carry tile ids
#define INS4(T0, T1, T2, T3, R) {                       \
    float n0_ = fmaxf(T0, R); float s0_ = fminf(T0, R); \
    float n1_ = fmaxf(T1, s0_); float s1_ = fminf(T1, s0_); \
    float n2_ = fmaxf(T2, s1_); float s2_ = fminf(T2, s1_); \
    float n3_ = fmaxf(T3, s2_);                         \
    T0 = n0_; T1 = n1_; T2 = n2_; T3 = n3_; }

// ---- Stage 2: fused {LDS-free barrier-free kNN sweep | insT->Tb} -----------
// knn blocks (0..2047): 64 rows x 4 waves, all waves sweep the same 512-cand
// slice (8 slices/batch -> 8192 waves = 32/CU). Single MFMA sweep; per
// (lane,j) packed sorted top-4 (tile id in low 6 mantissa bits); thr =
// 8th-of-16-lane-top1s - margin (valid upper bound on slice 8th-best dist);
// survivors append to GLOBAL surv via global atomics.
__global__ __launch_bounds__(256) void knn_kernel(const unsigned short* __restrict__ xbA,
                                                  const unsigned short* __restrict__ xbB,
                                                  const unsigned int* __restrict__ zbuf,
                                                  const float* __restrict__ insT,
                                                  unsigned int* __restrict__ Tb,
                                                  int* __restrict__ surv,
                                                  int* __restrict__ gcnt,
                                                  int doTb) {
    int bid = blockIdx.x;
    if (bid >= KNNBLKS) {                        // ---- prepT path ----
        int i = (bid - KNNBLKS) * 256 + threadIdx.x;
        int row = i / TDW;
        int dw  = i - row * TDW;
        int e   = dw * 2;
        const float* src = insT + (size_t)row * TT;
        float v0 = (e     < TT) ? src[e]     : 0.f;
        float v1 = (e + 1 < TT) ? src[e + 1] : 0.f;
        Tb[i] = rne_bf16(v0) | (rne_bf16(v1) << 16);
        return;
    }

    int tid   = threadIdx.x;
    int wid   = tid >> 6;
    int lane  = tid & 63;
    int grp4  = bid >> 3;                // row-group 0..255
    int slice = bid & 7;                 // 0..7
    int row0  = grp4 * RPB;
    int b     = row0 >> 12;
    int myrow = row0 + wid * 16;
    int cb    = b * NN + slice * CSW;
    int col   = lane & 15;
    int grp   = lane >> 4;
    int k0    = grp * 8;

    short8 A = *reinterpret_cast<const short8*>(xbA + (size_t)(myrow + col) * 32 + k0);
    bool on = (grp < 3);
    const char* p = on ? ((const char*)xbB + (size_t)(cb + col) * 48 + grp * 16)
                       : (const char*)zbuf;
    long incv = on ? 3072 : 0;
    f32x4 z = {0.f, 0.f, 0.f, 0.f};

    float t0v[4], t1v[4], t2v[4], t3v[4];
#pragma unroll
    for (int j = 0; j < 4; ++j) { t0v[j] = -FINF; t1v[j] = -FINF; t2v[j] = -FINF; t3v[j] = -FINF; }

    unsigned int tb4 = 0;
#pragma unroll 2
    for (int g = 0; g < NGRP; ++g) {
        short8 b0 = *reinterpret_cast<const short8*>(p);
        short8 b1 = *reinterpret_cast<const short8*>(p + 768);
        short8 b2 = *reinterpret_cast<const short8*>(p + 1536);
        short8 b3 = *reinterpret_cast<const short8*>(p + 2304);
        p += incv;
        f32x4 a0 = __builtin_amdgcn_mfma_f32_16x16x32_bf16(A, b0, z, 0, 0, 0);
        f32x4 a1 = __builtin_amdgcn_mfma_f32_16x16x32_bf16(A, b1, z, 0, 0, 0);
        f32x4 a2 = __builtin_amdgcn_mfma_f32_16x16x32_bf16(A, b2, z, 0, 0, 0);
        f32x4 a3 = __builtin_amdgcn_mfma_f32_16x16x32_bf16(A, b3, z, 0, 0, 0);
#pragma unroll
        for (int j = 0; j < 4; ++j) {
            float r0 = __uint_as_float((__float_as_uint(a0[j]) & ~63u) | (tb4 + 0u));
            float r1 = __uint_as_float((__float_as_uint(a1[j]) & ~63u) | (tb4 + 1u));
            float r2 = __uint_as_float((__float_as_uint(a2[j]) & ~63u) | (tb4 + 2u));
            float r3 = __uint_as_float((__float_as_uint(a3[j]) & ~63u) | (tb4 + 3u));
            INS4(t0v[j], t1v[j], t2v[j], t3v[j], r0)
            INS4(t0v[j], t1v[j], t2v[j], t3v[j], r1)
            INS4(t0v[j], t1v[j], t2v[j], t3v[j], r2)
            INS4(t0v[j], t1v[j], t2v[j], t3v[j], r3)
        }
        tb4 += 4;
    }

    // thr = (8th-largest of 16 lane top-1s) - margin; <= slice 8th-best acc
#pragma unroll
    for (int j = 0; j < 4; ++j) {
        float v = t0v[j];
        int cnt = 0;
#pragma unroll
        for (int m = 1; m < 16; ++m) {
            float o = __shfl_xor(v, m);
            cnt += (o > v) ? 1 : 0;
        }
        float bv = (cnt <= 7) ? v : FINF;
        bv = fminf(bv, __shfl_xor(bv, 1));
        bv = fminf(bv, __shfl_xor(bv, 2));
        bv = fminf(bv, __shfl_xor(bv, 4));
        bv = fminf(bv, __shfl_xor(bv, 8));
        float ta = bv - (0.35f + 0.007f * fabsf(bv));   // bf16 + pack-fuzz cover

        int rowg = row0 + wid * 16 + grp * 4 + j;
        size_t gix = (size_t)rowg * SL + slice;
        float q0 = t0v[j], q1 = t1v[j], q2 = t2v[j], q3 = t3v[j];
        int nb = (q0 >= ta) + (q1 >= ta) + (q2 >= ta) + (q3 >= ta);
        if (nb) {
            int base = atomicAdd(&gcnt[gix], nb);
            if (base < SCAP)
                surv[gix * SCAP + base] = cb + (int)((__float_as_uint(q0) & 63u) << 4) + col;
            if (nb > 1 && base + 1 < SCAP)
                surv[gix * SCAP + base + 1] = cb + (int)((__float_as_uint(q1) & 63u) << 4) + col;
            if (nb > 2 && base + 2 < SCAP)
                surv[gix * SCAP + base + 2] = cb + (int)((__float_as_uint(q2) & 63u) << 4) + col;
            if (nb > 3 && base + 3 < SCAP)
                surv[gix * SCAP + base + 3] = cb + (int)((__float_as_uint(q3) & 63u) << 4) + col;
        }
    }
}

// ---- select prologue: survivors -> exact fp32 top-7 (drop self) ------------
__device__ __forceinline__ void select7(int row, int lane,
                                        const int* __restrict__ surv,
                                        const int* __restrict__ gcnt,
                                        const float* __restrict__ xs,
                                        int* jn) {
    const float4* qp = (const float4*)(xs + (size_t)row * 24);
    float qv[20];
#pragma unroll
    for (int c = 0; c < 5; ++c) {
        float4 t = qp[c];
        qv[4*c] = t.x; qv[4*c+1] = t.y; qv[4*c+2] = t.z; qv[4*c+3] = t.w;
    }
    float d0 = FINF, d1 = FINF, d2 = FINF;
    int   g0 = 0x40000000 + lane * 4 + 0;
    int   g1 = 0x40000000 + lane * 4 + 1;
    int   g2 = 0x40000000 + lane * 4 + 2;
#pragma unroll
    for (int h = 0; h < 3; ++h) {
        int slot = lane + 64 * h;               // 0..191 = SL*SCAP
        int sl   = slot / SCAP;
        int k    = slot - sl * SCAP;
        int cnt  = gcnt[row * SL + sl]; cnt = (cnt > SCAP) ? SCAP : cnt;
        if (k < cnt) {
            int gg = surv[((size_t)row * SL + sl) * SCAP + k];
            const float4* xp = (const float4*)(xs + (size_t)gg * 24);
            float dot = 0.f;
#pragma unroll
            for (int c = 0; c < 5; ++c) {
                float4 xv = xp[c];
                dot = fmaf(qv[4*c+0], xv.x, dot);
                dot = fmaf(qv[4*c+1], xv.y, dot);
                dot = fmaf(qv[4*c+2], xv.z, dot);
                dot = fmaf(qv[4*c+3], xv.w, dot);
            }
            float r = fmaf(-2.f, dot, xs[(size_t)gg * 24 + 20]);
            if (gg == row) r = FINF;             // drop self by identity
            if (h == 0) { d0 = r; g0 = gg; }
            else if (h == 1) { d1 = r; g1 = gg; }
            else { d2 = r; g2 = gg; }
        }
    }
    // sort ascending (d0,g0) <= (d1,g1) <= (d2,g2)
    if (lexless(d1, g1, d0, g0)) { float t = d0; d0 = d1; d1 = t; int ti = g0; g0 = g1; g1 = ti; }
    if (lexless(d2, g2, d1, g1)) { float t = d1; d1 = d2; d2 = t; int ti = g1; g1 = g2; g2 = ti; }
    if (lexless(d1, g1, d0, g0)) { float t = d0; d0 = d1; d1 = t; int ti = g0; g0 = g1; g1 = ti; }
#pragma unroll
    for (int r = 0; r < KN; ++r) {
        float g = d0; int gj = g0;
#pragma unroll
        for (int off = 32; off >= 1; off >>= 1) {
            float od = __shfl_xor(g, off);
            int   oj = __shfl_xor(gj, off);
            if (lexless(od, oj, g, gj)) { g = od; gj = oj; }
        }
        jn[r] = gj;
        if (g0 == gj) {                          // unique owner pops
            d0 = d1; g0 = g1;
            d1 = d2; g1 = g2;
            d2 = FINF; g2 = 0x50000000 + lane * 8 + r;
        }
    }
}

// ---- Stage 3: wave-per-row: select + pair terms (bf16 T), XCD-swizzled -----
__global__ __launch_bounds__(256) void pairb_kernel(const float* __restrict__ xs,
                                                    const int* __restrict__ labels,
                                                    const unsigned int* __restrict__ Tb,
                                                    const int* __restrict__ surv,
                                                    const int* __restrict__ gcnt,
                                                    double* __restrict__ partials) {
    int wid  = threadIdx.x >> 6;
    int lane = threadIdx.x & 63;
    int bid  = blockIdx.x;                     // 4096 % 8 == 0 -> bijective
    int bswz = (bid & 7) * 512 + (bid >> 3);
    int row  = bswz * 4 + wid;
    int li   = labels[row];

    int jn[KN];
    select7(row, lane, surv, gcnt, xs, jn);

    const unsigned int* Ti = Tb + (size_t)row * TDW;
    unsigned int a0 = Ti[lane];
    unsigned int a1 = Ti[lane + 64];
    unsigned int a2 = (lane < 32) ? Ti[lane + 128] : 0u;
    float xi = (lane < 20) ? xs[(size_t)row * 24 + lane] : 0.f;

    unsigned int bv[KN][3];
    float xj[KN];
#pragma unroll
    for (int kk = 0; kk < KN; ++kk) {
        const unsigned int* Tj = Tb + (size_t)jn[kk] * TDW;
        bv[kk][0] = Tj[lane];
        bv[kk][1] = Tj[lane + 64];
        bv[kk][2] = (lane < 32) ? Tj[lane + 128] : 0u;
        xj[kk] = (lane < 20) ? xs[(size_t)jn[kk] * 24 + lane] : 0.f;
    }

    double acc = 0.0;
#pragma unroll
    for (int kk = 0; kk < KN; ++kk) {
        float td = 0.f;
        unsigned int aw[3] = {a0, a1, a2};
#pragma unroll
        for (int q = 0; q < 3; ++q) {
            unsigned int a = aw[q], bb = bv[kk][q];
            float dlo = __uint_as_float(a << 16)         - __uint_as_float(bb << 16);
            float dhi = __uint_as_float(a & 0xFFFF0000u) - __uint_as_float(bb & 0xFFFF0000u);
            td = fmaf(dlo, dlo, td);
            td = fmaf(dhi, dhi, td);
        }
        float df = xi - xj[kk];
        float dp = df * df;
#pragma unroll
        for (int off = 32; off >= 1; off >>= 1) {
            td += __shfl_xor(td, off);
            dp += __shfl_xor(dp, off);
        }
        if (lane == 0) {
            float eij = expf(-0.5f * dp);
            float sgn = (labels[jn[kk]] == li) ? eij : -eij;
            acc += (double)sgn * (double)td;
        }
    }
    __shared__ double wsum[4];
    if (lane == 0) wsum[wid] = acc;
    __syncthreads();
    if (threadIdx.x == 0)
        partials[blockIdx.x] = wsum[0] + wsum[1] + wsum[2] + wsum[3];
}

// ---- Stage 3': fp32 fallback (small workspace) -----------------------------
__global__ __launch_bounds__(256) void pair_f32_kernel(const float* __restrict__ xs,
                                                       const int* __restrict__ labels,
                                                       const float* __restrict__ insT,
                                                       const int* __restrict__ surv,
                                                       const int* __restrict__ gcnt,
                                                       double* __restrict__ partials) {
    int wid  = threadIdx.x >> 6;
    int lane = threadIdx.x & 63;
    int bid  = blockIdx.x;
    int bswz = (bid & 7) * 512 + (bid >> 3);
    int row  = bswz * 4 + wid;
    int li   = labels[row];

    int jn[KN];
    select7(row, lane, surv, gcnt, xs, jn);

    const float* Ti = insT + (size_t)row * TT;
    float tiv[5];
#pragma unroll
    for (int q = 0; q < 5; ++q) {
        int e = lane + 64 * q;
        tiv[q] = (e < TT) ? Ti[e] : 0.f;
    }
    float xi = (lane < 20) ? xs[(size_t)row * 24 + lane] : 0.f;
    double acc = 0.0;
#pragma unroll 1
    for (int kk = 0; kk < KN; ++kk) {
        int j = jn[kk];
        const float* Tj = insT + (size_t)j * TT;
        float td = 0.f;
#pragma unroll
        for (int q = 0; q < 5; ++q) {
            int e = lane + 64 * q;
            if (e < TT) { float df = tiv[q] - Tj[e]; td = fmaf(df, df, td); }
        }
        float dp = 0.f;
        if (lane < 20) { float df = xi - xs[(size_t)j * 24 + lane]; dp = df * df; }
#pragma unroll
        for (int off = 32; off >= 1; off >>= 1) {
            td += __shfl_xor(td, off);
            dp += __shfl_xor(dp, off);
        }
        if (lane == 0) {
            float eij = expf(-0.5f * dp);
            float sgn = (labels[j] == li) ? eij : -eij;
            acc += (double)sgn * (double)td;
        }
    }
    __shared__ double wsum[4];
    if (lane == 0) wsum[wid] = acc;
    __syncthreads();
    if (threadIdx.x == 0)
        partials[blockIdx.x] = wsum[0] + wsum[1] + wsum[2] + wsum[3];
}

// ---- Stage 4: deterministic final reduce + mean ----------------------------
__global__ __launch_bounds__(1024) void finalize_kernel(const double* __restrict__ partials,
                                                        int nparts, float* __restrict__ out) {
    __shared__ double red[1024];
    int t = threadIdx.x;
    double s = 0.0;
    for (int q = t; q < nparts; q += 1024) s += partials[q];
    red[t] = s;
    __syncthreads();
    for (int sft = 512; sft > 0; sft >>= 1) {
        if (t < sft) red[t] += red[t + sft];
        __syncthreads();
    }
    if (t == 0) out[0] = (float)(red[0] / (double)PAIRS);
}

extern "C" void kernel_launch(void* const* d_in, const int* in_sizes, int n_in,
                              void* d_out, int out_size, void* d_ws, size_t ws_size,
                              hipStream_t stream) {
    const float* logits = (const float*)d_in[0];
    const int*   labels = (const int*)d_in[1];
    const float* insT   = (const float*)d_in[2];
    float* out = (float*)d_out;

    // workspace layout (bytes)
    const size_t o_part = 0;                          // 32768
    const size_t o_gcnt = 32768;                      // 16384*8*4 = 524288
    const size_t o_surv = o_gcnt + 524288;            // 16384*192*4 = 12582912
    const size_t o_xs   = o_surv + 12582912;          // 1572864
    const size_t o_xbA  = o_xs + 1572864;             // 1048576
    const size_t o_xbB  = o_xbA + 1048576;            // 786432
    const size_t o_zb   = o_xbB + 786432;             // 4096
    const size_t o_Tb   = o_zb + 4096;                // 10485760
    const size_t need_Tb = o_Tb + 10485760;           // ~27 MB

    char* ws = (char*)d_ws;
    double*         partials = (double*)(ws + o_part);
    int*            gcnt     = (int*)(ws + o_gcnt);
    int*            surv     = (int*)(ws + o_surv);
    float*          xs       = (float*)(ws + o_xs);
    unsigned short* xbA      = (unsigned short*)(ws + o_xbA);
    unsigned short* xbB      = (unsigned short*)(ws + o_xbB);
    unsigned int*   zbuf     = (unsigned int*)(ws + o_zb);
    unsigned int*   Tb       = (unsigned int*)(ws + o_Tb);

    bool useTb = (ws_size >= need_Tb);
    int knn_grid = KNNBLKS + (useTb ? TBLKS : 0);

    hipLaunchKernelGGL(prep_kernel, dim3(NPTS / 256), dim3(256), 0, stream,
                       logits, xs, xbA, xbB, zbuf, gcnt);
    hipLaunchKernelGGL(knn_kernel, dim3(knn_grid), dim3(256), 0, stream,
                       xbA, xbB, zbuf, insT, Tb, surv, gcnt, (int)useTb);
    if (useTb)
        hipLaunchKernelGGL(pairb_kernel, dim3(NPTS / 4), dim3(256), 0, stream,
                           xs, labels, Tb, surv, gcnt, partials);
    else
        hipLaunchKernelGGL(pair_f32_kernel, dim3(NPTS / 4), dim3(256), 0, stream,
                           xs, labels, insT, surv, gcnt, partials);
    hipLaunchKernelGGL(finalize_kernel, dim3(1), dim3(1024), 0, stream,
                       partials, NPTS / 4, out);
}

// Round 18
// 83.839 us; speedup vs baseline: 1.3065x; 1.3065x over previous
//
#include <hip/hip_runtime.h>

#define BB 4
#define CC 17
#define NN 4096
#define KN 7
#define NPTS (BB*NN)             // 16384
#define PAIRS (NPTS*KN)          // 114688
#define TT (CC*CC)               // 289
#define FINF 3.4e38f
#define RPB 64                   // rows per knn block (4 waves x 16 rows)
#define SL 4                     // candidate slices per batch
#define CSW 1024                 // candidates per slice
#define NGRP 16                  // groups of 4 tiles (64 tiles)
#define SCAP 48                  // per-row survivor cap (LDS, all slices)
#define SPAD 49
#define TDW 160                  // bf16 T row: 320 elems = 160 dwords
#define KNNBLKS ((NPTS/RPB)*SL)  // 1024
#define TBLKS ((NPTS*TDW)/256)   // 10240

typedef float f32x4 __attribute__((ext_vector_type(4)));
typedef short short8 __attribute__((ext_vector_type(8)));

__device__ __forceinline__ unsigned int rne_bf16(float x) {
    unsigned int u = __float_as_uint(x);
    return (u + 0x7FFFu + ((u >> 16) & 1u)) >> 16;
}

__device__ __forceinline__ bool lexless(float ad, int ai, float bd, int bi) {
    return (ad < bd) || (ad == bd && ai < bi);
}

// ---- Stage 1: logits -> xs fp32[.][24], xbA bf16[.][32], xbB bf16[.][24], sq
__global__ __launch_bounds__(256) void prep_kernel(const float* __restrict__ logits,
                                                   float* __restrict__ xs,
                                                   unsigned short* __restrict__ xbA,
                                                   unsigned short* __restrict__ xbB,
                                                   float* __restrict__ sq,
                                                   unsigned int* __restrict__ zbuf) {
    if (blockIdx.x == 0) {                       // zero 3072 B zero-buffer
        for (int e = threadIdx.x; e < 768; e += 256) zbuf[e] = 0u;
    }
    int i = blockIdx.x * 256 + threadIdx.x;
    if (i >= NPTS) return;
    int b = i >> 12;
    int n = i & (NN - 1);
    const float* base = logits + (size_t)b * CC * NN + n;
    float v[24];
    float s = 0.f;
#pragma unroll
    for (int c = 0; c < CC; ++c) { v[c] = base[(size_t)c * NN]; s = fmaf(v[c], v[c], s); }
#pragma unroll
    for (int c = CC; c < 24; ++c) v[c] = 0.f;
    float4* dst = (float4*)(xs + (size_t)i * 24);
#pragma unroll
    for (int q = 0; q < 6; ++q)
        dst[q] = make_float4(v[4*q], v[4*q+1], v[4*q+2], v[4*q+3]);
    sq[i] = s;

    unsigned int w[12];
#pragma unroll
    for (int t = 0; t < 8; ++t)
        w[t] = rne_bf16(v[2*t]) | (rne_bf16(v[2*t+1]) << 16);
#pragma unroll
    for (int t = 9; t < 12; ++t) w[t] = 0u;
    // A view (64 B rows): slot16 = v16, slot17 = 1.0, rest zero
    w[8] = rne_bf16(v[16]) | (0x3F80u << 16);
    uint4* da = (uint4*)(xbA + (size_t)i * 32);
    da[0] = make_uint4(w[0], w[1], w[2], w[3]);
    da[1] = make_uint4(w[4], w[5], w[6], w[7]);
    da[2] = make_uint4(w[8], w[9], w[10], w[11]);
    da[3] = make_uint4(0u, 0u, 0u, 0u);
    // B view (48 B rows): slot17 = -sq/2 => acc = dot - sq_c/2
    w[8] = rne_bf16(v[16]) | (rne_bf16(-0.5f * s) << 16);
    uint4* db = (uint4*)(xbB + (size_t)i * 24);
    db[0] = make_uint4(w[0], w[1], w[2], w[3]);
    db[1] = make_uint4(w[4], w[5], w[6], w[7]);
    db[2] = make_uint4(w[8], w[9], w[10], w[11]);
}

// branchless sorted-desc top-2 insert; packed floats carry tile ids
#define INS2(T0, T1, R) {                               \
    float n0_ = fmaxf(T0, R); float s0_ = fminf(T0, R); \
    float n1_ = fmaxf(T1, s0_);                         \
    T0 = n0_; T1 = n1_; }

// ---- Stage 2: fused {kNN single-pass top-2 | insT->Tb conversion} ----------
// knn blocks (0..1023, slice-major): 64 rows x 4 waves, all waves sweep the
// same 1024-cand slice. One MFMA sweep; per (lane,j) packed sorted top-2
// (tile id in low 6 mantissa bits). thr = 8th-of-16-lane-top1s - margin
// (valid: >=8 survivors/slice). Append decoded survivors -> exact fp32
// re-rank -> per-(row,slice) top-8 -> parts.
__global__ __launch_bounds__(256) void knn_kernel(const unsigned short* __restrict__ xbA,
                                                  const unsigned short* __restrict__ xbB,
                                                  const float* __restrict__ sq,
                                                  const float* __restrict__ xs,
                                                  const unsigned int* __restrict__ zbuf,
                                                  const float* __restrict__ insT,
                                                  unsigned int* __restrict__ Tb,
                                                  float* __restrict__ parts_d,
                                                  int* __restrict__ parts_i,
                                                  int doTb) {
    __shared__ int   scnt[RPB];
    __shared__ int   slist[RPB][SPAD];
    __shared__ float srank[RPB][SPAD];

    int bid = blockIdx.x;
    if (bid >= KNNBLKS) {                        // ---- prepT path ----
        int i = (bid - KNNBLKS) * 256 + threadIdx.x;
        int row = i / TDW;
        int dw  = i - row * TDW;
        int e   = dw * 2;
        const float* src = insT + (size_t)row * TT;
        float v0 = (e     < TT) ? src[e]     : 0.f;
        float v1 = (e + 1 < TT) ? src[e + 1] : 0.f;
        Tb[i] = rne_bf16(v0) | (rne_bf16(v1) << 16);
        return;
    }

    int tid   = threadIdx.x;
    int wid   = tid >> 6;
    int lane  = tid & 63;
    int slice = bid >> 8;                // slice-major: XCD neighbors share slice
    int grp4  = bid & 255;
    int row0  = grp4 * RPB;
    int b     = row0 >> 12;
    int myrow = row0 + wid * 16;
    int cb    = b * NN + slice * CSW;
    int col   = lane & 15;
    int grp   = lane >> 4;
    int k0    = grp * 8;

    if (tid < RPB) scnt[tid] = 0;
    __syncthreads();

    short8 A = *reinterpret_cast<const short8*>(xbA + (size_t)(myrow + col) * 32 + k0);
    bool on = (grp < 3);
    const char* p = on ? ((const char*)xbB + (size_t)(cb + col) * 48 + grp * 16)
                       : (const char*)zbuf;
    long incv = on ? 3072 : 0;
    f32x4 z = {0.f, 0.f, 0.f, 0.f};

    float t0v[4], t1v[4];
#pragma unroll
    for (int j = 0; j < 4; ++j) { t0v[j] = -FINF; t1v[j] = -FINF; }

    unsigned int tb4 = 0;
#pragma unroll 2
    for (int g = 0; g < NGRP; ++g) {
        short8 b0 = *reinterpret_cast<const short8*>(p);
        short8 b1 = *reinterpret_cast<const short8*>(p + 768);
        short8 b2 = *reinterpret_cast<const short8*>(p + 1536);
        short8 b3 = *reinterpret_cast<const short8*>(p + 2304);
        p += incv;
        f32x4 a0 = __builtin_amdgcn_mfma_f32_16x16x32_bf16(A, b0, z, 0, 0, 0);
        f32x4 a1 = __builtin_amdgcn_mfma_f32_16x16x32_bf16(A, b1, z, 0, 0, 0);
        f32x4 a2 = __builtin_amdgcn_mfma_f32_16x16x32_bf16(A, b2, z, 0, 0, 0);
        f32x4 a3 = __builtin_amdgcn_mfma_f32_16x16x32_bf16(A, b3, z, 0, 0, 0);
#pragma unroll
        for (int j = 0; j < 4; ++j) {
            float r0 = __uint_as_float((__float_as_uint(a0[j]) & ~63u) | (tb4 + 0u));
            float r1 = __uint_as_float((__float_as_uint(a1[j]) & ~63u) | (tb4 + 1u));
            float r2 = __uint_as_float((__float_as_uint(a2[j]) & ~63u) | (tb4 + 2u));
            float r3 = __uint_as_float((__float_as_uint(a3[j]) & ~63u) | (tb4 + 3u));
            INS2(t0v[j], t1v[j], r0)
            INS2(t0v[j], t1v[j], r1)
            INS2(t0v[j], t1v[j], r2)
            INS2(t0v[j], t1v[j], r3)
        }
        tb4 += 4;
    }

    // thr = (8th-largest of 16 lane top-1s) - margin; <= slice 8th-best
#pragma unroll
    for (int j = 0; j < 4; ++j) {
        float v = t0v[j];
        int cnt = 0;
#pragma unroll
        for (int m = 1; m < 16; ++m) {
            float o = __shfl_xor(v, m);
            cnt += (o > v) ? 1 : 0;
        }
        float bv = (cnt <= 7) ? v : FINF;
        bv = fminf(bv, __shfl_xor(bv, 1));
        bv = fminf(bv, __shfl_xor(bv, 2));
        bv = fminf(bv, __shfl_xor(bv, 4));
        bv = fminf(bv, __shfl_xor(bv, 8));
        float ta = bv - (0.35f + 0.007f * fabsf(bv));   // bf16 + pack-fuzz cover

        int rloc = wid * 16 + grp * 4 + j;
        float q0 = t0v[j], q1 = t1v[j];
        int nb = (q0 >= ta) + (q1 >= ta);
        if (nb) {
            int base = atomicAdd(&scnt[rloc], nb);
            if (base < SCAP)
                slist[rloc][base] = cb + (int)((__float_as_uint(q0) & 63u) << 4) + col;
            if (nb > 1 && base + 1 < SCAP)
                slist[rloc][base + 1] = cb + (int)((__float_as_uint(q1) & 63u) << 4) + col;
        }
    }
    __syncthreads();

    // ---- exact fp32 rank of survivors; 4 threads per row ----
    {
        int rowl = tid >> 2;
        int l4   = tid & 3;
        int rowg = row0 + rowl;
        int cnt  = scnt[rowl]; cnt = (cnt > SCAP) ? SCAP : cnt;
        const float4* qp = (const float4*)(xs + (size_t)rowg * 24);
        float qv[20];
#pragma unroll
        for (int c = 0; c < 5; ++c) {
            float4 t = qp[c];
            qv[4*c] = t.x; qv[4*c+1] = t.y; qv[4*c+2] = t.z; qv[4*c+3] = t.w;
        }
#pragma unroll
        for (int h = 0; h < 12; ++h) {
            int slot = l4 + 4 * h;
            if (slot < cnt) {
                int g = slist[rowl][slot];
                const float4* xp = (const float4*)(xs + (size_t)g * 24);
                float dot = 0.f;
#pragma unroll
                for (int c = 0; c < 5; ++c) {
                    float4 xv = xp[c];
                    dot = fmaf(qv[4*c+0], xv.x, dot);
                    dot = fmaf(qv[4*c+1], xv.y, dot);
                    dot = fmaf(qv[4*c+2], xv.z, dot);
                    dot = fmaf(qv[4*c+3], xv.w, dot);
                }
                srank[rowl][slot] = fmaf(-2.f, dot, sq[g]);  // self keeps rank -sq
            }
        }
    }
    __syncthreads();

    // ---- 64 lanes (lane = row), serial top-8 -> global parts ----
    if (tid < RPB) {
        int rowl = tid;
        int rowg = row0 + rowl;
        int cnt  = scnt[rowl]; cnt = (cnt > SCAP) ? SCAP : cnt;
        float bd[8]; int bi[8];
#pragma unroll
        for (int k = 0; k < 8; ++k) { bd[k] = FINF; bi[k] = 0x40000000 + (rowg << 3) + k; }
        for (int s = 0; s < cnt; ++s) {
            float r = srank[rowl][s];
            int   g = slist[rowl][s];
            if (lexless(r, g, bd[7], bi[7])) {
                bd[7] = r; bi[7] = g;
#pragma unroll
                for (int k = 7; k >= 1; --k) {
                    if (lexless(bd[k], bi[k], bd[k-1], bi[k-1])) {
                        float td = bd[k]; bd[k] = bd[k-1]; bd[k-1] = td;
                        int   ti = bi[k]; bi[k] = bi[k-1]; bi[k-1] = ti;
                    }
                }
            }
        }
        size_t ob = ((size_t)rowg * SL + slice) * 8;
#pragma unroll
        for (int k = 0; k < 8; ++k) { parts_d[ob + k] = bd[k]; parts_i[ob + k] = bi[k]; }
    }
}

// ---- merge prologue: 32 (d,i) entries -> 7 neighbors (drop self) -----------
__device__ __forceinline__ void merge32(int row, int lane,
                                        const float* __restrict__ parts_d,
                                        const int* __restrict__ parts_i,
                                        int* jn) {
    float d = FINF;
    int   gi = 0x50000000 + lane;
    if (lane < 32) {
        size_t ob = (size_t)row * 32 + lane;
        d  = parts_d[ob];
        gi = parts_i[ob];
        if (gi == row) d = FINF;             // drop self by identity
    }
#pragma unroll
    for (int r = 0; r < KN; ++r) {
        float g = d; int gj = gi;
#pragma unroll
        for (int off = 32; off >= 1; off >>= 1) {
            float od = __shfl_xor(g, off);
            int   oj = __shfl_xor(gj, off);
            if (lexless(od, oj, g, gj)) { g = od; gj = oj; }
        }
        jn[r] = gj;
        if (gi == gj) { d = FINF; gi = 0x58000000 + lane * 8 + r; }
    }
}

// ---- Stage 3: wave-per-row: merge + pair terms (bf16 T), XCD-swizzled ------
__global__ __launch_bounds__(256) void pairb_kernel(const float* __restrict__ xs,
                                                    const int* __restrict__ labels,
                                                    const unsigned int* __restrict__ Tb,
                                                    const float* __restrict__ parts_d,
                                                    const int* __restrict__ parts_i,
                                                    double* __restrict__ partials) {
    int wid  = threadIdx.x >> 6;
    int lane = threadIdx.x & 63;
    int bid  = blockIdx.x;                     // 4096 % 8 == 0 -> bijective
    int bswz = (bid & 7) * 512 + (bid >> 3);
    int row  = bswz * 4 + wid;
    int li   = labels[row];

    int jn[KN];
    merge32(row, lane, parts_d, parts_i, jn);

    const unsigned int* Ti = Tb + (size_t)row * TDW;
    unsigned int a0 = Ti[lane];
    unsigned int a1 = Ti[lane + 64];
    unsigned int a2 = (lane < 32) ? Ti[lane + 128] : 0u;
    float xi = (lane < 20) ? xs[(size_t)row * 24 + lane] : 0.f;

    unsigned int bv[KN][3];
    float xj[KN];
#pragma unroll
    for (int kk = 0; kk < KN; ++kk) {
        const unsigned int* Tj = Tb + (size_t)jn[kk] * TDW;
        bv[kk][0] = Tj[lane];
        bv[kk][1] = Tj[lane + 64];
        bv[kk][2] = (lane < 32) ? Tj[lane + 128] : 0u;
        xj[kk] = (lane < 20) ? xs[(size_t)jn[kk] * 24 + lane] : 0.f;
    }

    double acc = 0.0;
#pragma unroll
    for (int kk = 0; kk < KN; ++kk) {
        float td = 0.f;
        unsigned int aw[3] = {a0, a1, a2};
#pragma unroll
        for (int q = 0; q < 3; ++q) {
            unsigned int a = aw[q], bb = bv[kk][q];
            float dlo = __uint_as_float(a << 16)         - __uint_as_float(bb << 16);
            float dhi = __uint_as_float(a & 0xFFFF0000u) - __uint_as_float(bb & 0xFFFF0000u);
            td = fmaf(dlo, dlo, td);
            td = fmaf(dhi, dhi, td);
        }
        float df = xi - xj[kk];
        float dp = df * df;
#pragma unroll
        for (int off = 32; off >= 1; off >>= 1) {
            td += __shfl_xor(td, off);
            dp += __shfl_xor(dp, off);
        }
        if (lane == 0) {
            float eij = expf(-0.5f * dp);
            float sgn = (labels[jn[kk]] == li) ? eij : -eij;
            acc += (double)sgn * (double)td;
        }
    }
    __shared__ double wsum[4];
    if (lane == 0) wsum[wid] = acc;
    __syncthreads();
    if (threadIdx.x == 0)
        partials[blockIdx.x] = wsum[0] + wsum[1] + wsum[2] + wsum[3];
}

// ---- Stage 3': fp32 fallback (small workspace) -----------------------------
__global__ __launch_bounds__(256) void pair_f32_kernel(const float* __restrict__ xs,
                                                       const int* __restrict__ labels,
                                                       const float* __restrict__ insT,
                                                       const float* __restrict__ parts_d,
                                                       const int* __restrict__ parts_i,
                                                       double* __restrict__ partials) {
    int wid  = threadIdx.x >> 6;
    int lane = threadIdx.x & 63;
    int bid  = blockIdx.x;
    int bswz = (bid & 7) * 512 + (bid >> 3);
    int row  = bswz * 4 + wid;
    int li   = labels[row];

    int jn[KN];
    merge32(row, lane, parts_d, parts_i, jn);

    const float* Ti = insT + (size_t)row * TT;
    float tiv[5];
#pragma unroll
    for (int q = 0; q < 5; ++q) {
        int e = lane + 64 * q;
        tiv[q] = (e < TT) ? Ti[e] : 0.f;
    }
    float xi = (lane < 20) ? xs[(size_t)row * 24 + lane] : 0.f;
    double acc = 0.0;
#pragma unroll 1
    for (int kk = 0; kk < KN; ++kk) {
        int j = jn[kk];
        const float* Tj = insT + (size_t)j * TT;
        float td = 0.f;
#pragma unroll
        for (int q = 0; q < 5; ++q) {
            int e = lane + 64 * q;
            if (e < TT) { float df = tiv[q] - Tj[e]; td = fmaf(df, df, td); }
        }
        float dp = 0.f;
        if (lane < 20) { float df = xi - xs[(size_t)j * 24 + lane]; dp = df * df; }
#pragma unroll
        for (int off = 32; off >= 1; off >>= 1) {
            td += __shfl_xor(td, off);
            dp += __shfl_xor(dp, off);
        }
        if (lane == 0) {
            float eij = expf(-0.5f * dp);
            float sgn = (labels[j] == li) ? eij : -eij;
            acc += (double)sgn * (double)td;
        }
    }
    __shared__ double wsum[4];
    if (lane == 0) wsum[wid] = acc;
    __syncthreads();
    if (threadIdx.x == 0)
        partials[blockIdx.x] = wsum[0] + wsum[1] + wsum[2] + wsum[3];
}

// ---- Stage 4: deterministic final reduce + mean ----------------------------
__global__ __launch_bounds__(1024) void finalize_kernel(const double* __restrict__ partials,
                                                        int nparts, float* __restrict__ out) {
    __shared__ double red[1024];
    int t = threadIdx.x;
    double s = 0.0;
    for (int q = t; q < nparts; q += 1024) s += partials[q];
    red[t] = s;
    __syncthreads();
    for (int sft = 512; sft > 0; sft >>= 1) {
        if (t < sft) red[t] += red[t + sft];
        __syncthreads();
    }
    if (t == 0) out[0] = (float)(red[0] / (double)PAIRS);
}

extern "C" void kernel_launch(void* const* d_in, const int* in_sizes, int n_in,
                              void* d_out, int out_size, void* d_ws, size_t ws_size,
                              hipStream_t stream) {
    const float* logits = (const float*)d_in[0];
    const int*   labels = (const int*)d_in[1];
    const float* insT   = (const float*)d_in[2];
    float* out = (float*)d_out;

    // workspace layout (bytes)
    const size_t o_part = 0;                          // 32768
    const size_t o_pd   = 32768;                      // parts_d 2 MB
    const size_t o_pi   = o_pd + 2097152;             // parts_i 2 MB
    const size_t o_sq   = o_pi + 2097152;             // 65536
    const size_t o_xs   = o_sq + 65536;               // 1572864
    const size_t o_xbA  = o_xs + 1572864;             // 1048576
    const size_t o_xbB  = o_xbA + 1048576;            // 786432
    const size_t o_zb   = o_xbB + 786432;             // 4096
    const size_t o_Tb   = o_zb + 4096;                // 10485760
    const size_t need_Tb = o_Tb + 10485760;           // ~18.1 MB

    char* ws = (char*)d_ws;
    double*         partials = (double*)(ws + o_part);
    float*          parts_d  = (float*)(ws + o_pd);
    int*            parts_i  = (int*)(ws + o_pi);
    float*          sq       = (float*)(ws + o_sq);
    float*          xs       = (float*)(ws + o_xs);
    unsigned short* xbA      = (unsigned short*)(ws + o_xbA);
    unsigned short* xbB      = (unsigned short*)(ws + o_xbB);
    unsigned int*   zbuf     = (unsigned int*)(ws + o_zb);
    unsigned int*   Tb       = (unsigned int*)(ws + o_Tb);

    bool useTb = (ws_size >= need_Tb);
    int knn_grid = KNNBLKS + (useTb ? TBLKS : 0);

    hipLaunchKernelGGL(prep_kernel, dim3(NPTS / 256), dim3(256), 0, stream,
                       logits, xs, xbA, xbB, sq, zbuf);
    hipLaunchKernelGGL(knn_kernel, dim3(knn_grid), dim3(256), 0, stream,
                       xbA, xbB, sq, xs, zbuf, insT, Tb, parts_d, parts_i, (int)useTb);
    if (useTb)
        hipLaunchKernelGGL(pairb_kernel, dim3(NPTS / 4), dim3(256), 0, stream,
                           xs, labels, Tb, parts_d, parts_i, partials);
    else
        hipLaunchKernelGGL(pair_f32_kernel, dim3(NPTS / 4), dim3(256), 0, stream,
                           xs, labels, insT, parts_d, parts_i, partials);
    hipLaunchKernelGGL(finalize_kernel, dim3(1), dim3(1024), 0, stream,
                       partials, NPTS / 4, out);
}